// Round 1
// 482.026 us; speedup vs baseline: 1.0530x; 1.0530x over previous
//
#include <hip/hip_runtime.h>

// StarLoss: mean over (B,N) of
//   (1/sqrt(lam1)+eps)*d1 + (1/sqrt(lam2)+eps)*d2 + 0.5*omega*(lam1+lam2)
// where d1,d2 are GLOBAL sums. Decomposes into 5 scalar sums S1..S5;
// final = (S1*S3 + S2*S4 + 0.5*S5)/M.
//
// R5: lane-DENSE mapping. R4 (quad-per-thread) had pred loads with 32B lane
// stride (16 lines/instr, half used) and cov loads with 64B lane stride
// (32 lines/instr, quarter used) -> 192 line-touches per wave-iter for 64
// unique lines. Theory: the 3.34 TB/s pin is a per-CU line-concurrency cap;
// redundant touches burn MSHR/L1-tag slots. R5 maps ONE element per thread
// per step: cov = dense dwordx4, pred/tgt = dense dwordx2 -> every VMEM
// instruction touches only unique lines. 4-step unroll keeps 12 loads
// (64 unique lines) in flight per wave. NT loads kept identical to R4 so
// the mapping is the only variable.

#define NBLOCKS  4096
#define NTHREADS 256
#define NACC     5
#define M_ELEMS  16777216                 // 4096*4096 elements
#define STRIDE   (NBLOCKS * NTHREADS)     // 1,048,576 threads
#define STEPS    (M_ELEMS / STRIDE)       // 16 elements per thread
#define UNROLL   4                        // 12 loads in flight per thread
#define EPS      1e-5
#define OMEGA    1.0

typedef float f4 __attribute__((ext_vector_type(4)));   // native: NT-loadable
typedef float f2 __attribute__((ext_vector_type(2)));

__device__ __forceinline__ f4 nt_load4(const f4* p) {
    return __builtin_nontemporal_load(p);
}
__device__ __forceinline__ f2 nt_load2(const f2* p) {
    return __builtin_nontemporal_load(p);
}

__device__ __forceinline__ float wave_reduce_f(float v) {
    #pragma unroll
    for (int off = 32; off > 0; off >>= 1) v += __shfl_down(v, off, 64);
    return v;
}

// one 2x2 eigen-element: cov f4 c = [a, b, b, d], residual (dx, dy)
__device__ __forceinline__ void star_elem(
    f4 c, float dx, float dy,
    float& s1, float& s2, float& s3, float& s4, float& s5)
{
    const float a = c.x, b = c.y, d = c.w;
    float mean  = 0.5f * (a + d);
    float hd    = 0.5f * (a - d);
    float delta = sqrtf(hd * hd + b * b);
    float lam1  = mean + delta;
    float lam2  = mean - delta;           // >= 0.1 (PSD + 0.1*I)

    bool diag = fabsf(b) < 1e-12f;
    bool a_ge = (a >= d);
    float vx = diag ? (a_ge ? 1.0f : 0.0f) : b;
    float vy = diag ? (a_ge ? 0.0f : 1.0f) : (lam1 - a);
    float inv_n = rsqrtf(vx * vx + vy * vy);
    vx *= inv_n;
    vy *= inv_n;

    float r1 = vx * dx + vy * dy;
    float r2 = vx * dy - vy * dx;

    s1 += r1 * r1;
    s2 += r2 * r2;
    s3 += rsqrtf(lam1);
    s4 += rsqrtf(lam2);
    s5 += a + d;                          // trace = lam1 + lam2
}

__global__ __launch_bounds__(NTHREADS) void star_partial(
    const f2* __restrict__ pred,   // M f2 (1 elem each) -- dense per lane
    const f4* __restrict__ cov,    // M f4 (1 elem each) -- dense per lane
    const f2* __restrict__ tgt,    // M f2
    float* __restrict__ partials)  // NBLOCKS * NACC
{
    float s1 = 0.f, s2 = 0.f, s3 = 0.f, s4 = 0.f, s5 = 0.f;
    const int tid = blockIdx.x * NTHREADS + threadIdx.x;

    #pragma unroll 1
    for (int g = 0; g < STEPS; g += UNROLL) {
        f4 c[UNROLL];
        f2 p[UNROLL], t[UNROLL];
        // all indices compile-time after full unroll (no scratch spill)
        #pragma unroll
        for (int u = 0; u < UNROLL; ++u) {
            const int e = (g + u) * STRIDE + tid;
            c[u] = nt_load4(&cov[e]);
            p[u] = nt_load2(&pred[e]);
            t[u] = nt_load2(&tgt[e]);
        }
        #pragma unroll
        for (int u = 0; u < UNROLL; ++u)
            star_elem(c[u], p[u].x - t[u].x, p[u].y - t[u].y,
                      s1, s2, s3, s4, s5);
    }

    float v[NACC] = {s1, s2, s3, s4, s5};
    #pragma unroll
    for (int k = 0; k < NACC; ++k) v[k] = wave_reduce_f(v[k]);

    __shared__ float red[NTHREADS / 64][NACC];
    const int lane = threadIdx.x & 63;
    const int wid  = threadIdx.x >> 6;
    if (lane == 0) {
        #pragma unroll
        for (int k = 0; k < NACC; ++k) red[wid][k] = v[k];
    }
    __syncthreads();
    if (threadIdx.x == 0) {
        #pragma unroll
        for (int k = 0; k < NACC; ++k) {
            float acc = 0.f;
            #pragma unroll
            for (int w = 0; w < NTHREADS / 64; ++w) acc += red[w][k];
            partials[blockIdx.x * NACC + k] = acc;
        }
    }
}

__global__ __launch_bounds__(NTHREADS) void star_final(
    const float* __restrict__ partials, float* __restrict__ out, int nblocks)
{
    double acc[NACC] = {0, 0, 0, 0, 0};
    for (int i = threadIdx.x; i < nblocks; i += NTHREADS) {
        #pragma unroll
        for (int k = 0; k < NACC; ++k) acc[k] += (double)partials[i * NACC + k];
    }

    #pragma unroll
    for (int k = 0; k < NACC; ++k) {
        #pragma unroll
        for (int off = 32; off > 0; off >>= 1)
            acc[k] += __shfl_down(acc[k], off, 64);
    }

    __shared__ double red[NTHREADS / 64][NACC];
    const int lane = threadIdx.x & 63;
    const int wid  = threadIdx.x >> 6;
    if (lane == 0) {
        #pragma unroll
        for (int k = 0; k < NACC; ++k) red[wid][k] = acc[k];
    }
    __syncthreads();

    if (threadIdx.x == 0) {
        double S[NACC];
        #pragma unroll
        for (int k = 0; k < NACC; ++k) {
            double t = 0.0;
            #pragma unroll
            for (int w = 0; w < NTHREADS / 64; ++w) t += red[w][k];
            S[k] = t;
        }
        const double M  = (double)M_ELEMS;
        const double S3 = S[2] + M * EPS;   // sum of (1/sqrt(lam1) + eps)
        const double S4 = S[3] + M * EPS;
        double loss = (S[0] * S3 + S[1] * S4 + 0.5 * OMEGA * S[4]) / M;
        out[0] = (float)loss;
    }
}

extern "C" void kernel_launch(void* const* d_in, const int* in_sizes, int n_in,
                              void* d_out, int out_size, void* d_ws, size_t ws_size,
                              hipStream_t stream) {
    const f2* pred = (const f2*)d_in[0];   // (B,N,2)   = M f2
    const f4* cov  = (const f4*)d_in[1];   // (B,N,2,2) = M f4
    const f2* tgt  = (const f2*)d_in[2];   // (B,N,2)   = M f2
    float* out      = (float*)d_out;
    float* partials = (float*)d_ws;        // NBLOCKS*NACC floats (80 KB)

    star_partial<<<NBLOCKS, NTHREADS, 0, stream>>>(pred, cov, tgt, partials);
    star_final<<<1, NTHREADS, 0, stream>>>(partials, out, NBLOCKS);
}

// Round 2
// 481.276 us; speedup vs baseline: 1.0546x; 1.0016x over previous
//
#include <hip/hip_runtime.h>

// StarLoss: mean over (B,N) of
//   (1/sqrt(lam1)+eps)*d1 + (1/sqrt(lam2)+eps)*d2 + 0.5*omega*(lam1+lam2)
// where d1,d2 are GLOBAL sums. Decomposes into 5 scalar sums S1..S5;
// final = (S1*S3 + S2*S4 + 0.5*S5)/M.
//
// R6: ping-pong software pipeline on top of R5's lane-dense mapping.
// R5 (482us total, kernel ~130us = 4.1 TB/s read) issues 12 loads, computes
// 4 elements, then issues the next 12 -- outstanding loads drain to ~0 at the
// tail of every compute phase (loop-carried register reuse + unroll 1 forbids
// compiler pipelining). R6 double-buffers the staging registers (two NAMED
// Stage structs -> compile-time indexing, no scratch) so every compute phase
// runs with the next group's 6 loads (16 unique cache lines) in flight.
// Group size 2 keeps both buffers at 32 VGPRs total -> <=64 VGPR, 32 waves/CU.
// Addresses, NT flags, and math identical to R5; pipelining is the only
// variable.

#define NBLOCKS  4096
#define NTHREADS 256
#define NACC     5
#define M_ELEMS  16777216                 // 4096*4096 elements
#define STRIDE   (NBLOCKS * NTHREADS)     // 1,048,576 threads
#define STEPS    (M_ELEMS / STRIDE)       // 16 elements per thread
#define GELEMS   2                        // elements per pipeline stage
#define NGROUPS  (STEPS / GELEMS)         // 8 (even -> clean 2-stage epilogue)
#define EPS      1e-5
#define OMEGA    1.0

typedef float f4 __attribute__((ext_vector_type(4)));   // native: NT-loadable
typedef float f2 __attribute__((ext_vector_type(2)));

struct Stage {
    f4 c[GELEMS];
    f2 p[GELEMS];
    f2 t[GELEMS];
};

__device__ __forceinline__ void stage_load(
    Stage& s, const f4* __restrict__ cov, const f2* __restrict__ pred,
    const f2* __restrict__ tgt, int base)
{
    #pragma unroll
    for (int u = 0; u < GELEMS; ++u) {
        const int e = base + u * STRIDE;
        s.c[u] = __builtin_nontemporal_load(&cov[e]);
        s.p[u] = __builtin_nontemporal_load(&pred[e]);
        s.t[u] = __builtin_nontemporal_load(&tgt[e]);
    }
}

// one 2x2 eigen-element: cov f4 c = [a, b, b, d], residual (dx, dy)
__device__ __forceinline__ void star_elem(
    f4 c, float dx, float dy,
    float& s1, float& s2, float& s3, float& s4, float& s5)
{
    const float a = c.x, b = c.y, d = c.w;
    float mean  = 0.5f * (a + d);
    float hd    = 0.5f * (a - d);
    float delta = sqrtf(hd * hd + b * b);
    float lam1  = mean + delta;
    float lam2  = mean - delta;           // >= 0.1 (PSD + 0.1*I)

    bool diag = fabsf(b) < 1e-12f;
    bool a_ge = (a >= d);
    float vx = diag ? (a_ge ? 1.0f : 0.0f) : b;
    float vy = diag ? (a_ge ? 0.0f : 1.0f) : (lam1 - a);
    float inv_n = rsqrtf(vx * vx + vy * vy);
    vx *= inv_n;
    vy *= inv_n;

    float r1 = vx * dx + vy * dy;
    float r2 = vx * dy - vy * dx;

    s1 += r1 * r1;
    s2 += r2 * r2;
    s3 += rsqrtf(lam1);
    s4 += rsqrtf(lam2);
    s5 += a + d;                          // trace = lam1 + lam2
}

__device__ __forceinline__ void stage_compute(
    const Stage& s,
    float& s1, float& s2, float& s3, float& s4, float& s5)
{
    #pragma unroll
    for (int u = 0; u < GELEMS; ++u)
        star_elem(s.c[u], s.p[u].x - s.t[u].x, s.p[u].y - s.t[u].y,
                  s1, s2, s3, s4, s5);
}

__device__ __forceinline__ float wave_reduce_f(float v) {
    #pragma unroll
    for (int off = 32; off > 0; off >>= 1) v += __shfl_down(v, off, 64);
    return v;
}

__global__ __launch_bounds__(NTHREADS) void star_partial(
    const f2* __restrict__ pred,   // M f2 (1 elem each) -- dense per lane
    const f4* __restrict__ cov,    // M f4 (1 elem each) -- dense per lane
    const f2* __restrict__ tgt,    // M f2
    float* __restrict__ partials)  // NBLOCKS * NACC
{
    float s1 = 0.f, s2 = 0.f, s3 = 0.f, s4 = 0.f, s5 = 0.f;
    const int tid = blockIdx.x * NTHREADS + threadIdx.x;

    Stage stA, stB;
    stage_load(stA, cov, pred, tgt, tid);           // group 0

    // groups processed in pairs: load(g+1) | compute(g) | load(g+2) | compute(g+1)
    #pragma unroll
    for (int g = 0; g < NGROUPS; g += 2) {
        stage_load(stB, cov, pred, tgt, tid + (g + 1) * GELEMS * STRIDE);
        stage_compute(stA, s1, s2, s3, s4, s5);
        if (g + 2 < NGROUPS)
            stage_load(stA, cov, pred, tgt, tid + (g + 2) * GELEMS * STRIDE);
        stage_compute(stB, s1, s2, s3, s4, s5);
    }

    float v[NACC] = {s1, s2, s3, s4, s5};
    #pragma unroll
    for (int k = 0; k < NACC; ++k) v[k] = wave_reduce_f(v[k]);

    __shared__ float red[NTHREADS / 64][NACC];
    const int lane = threadIdx.x & 63;
    const int wid  = threadIdx.x >> 6;
    if (lane == 0) {
        #pragma unroll
        for (int k = 0; k < NACC; ++k) red[wid][k] = v[k];
    }
    __syncthreads();
    if (threadIdx.x == 0) {
        #pragma unroll
        for (int k = 0; k < NACC; ++k) {
            float acc = 0.f;
            #pragma unroll
            for (int w = 0; w < NTHREADS / 64; ++w) acc += red[w][k];
            partials[blockIdx.x * NACC + k] = acc;
        }
    }
}

__global__ __launch_bounds__(NTHREADS) void star_final(
    const float* __restrict__ partials, float* __restrict__ out, int nblocks)
{
    double acc[NACC] = {0, 0, 0, 0, 0};
    for (int i = threadIdx.x; i < nblocks; i += NTHREADS) {
        #pragma unroll
        for (int k = 0; k < NACC; ++k) acc[k] += (double)partials[i * NACC + k];
    }

    #pragma unroll
    for (int k = 0; k < NACC; ++k) {
        #pragma unroll
        for (int off = 32; off > 0; off >>= 1)
            acc[k] += __shfl_down(acc[k], off, 64);
    }

    __shared__ double red[NTHREADS / 64][NACC];
    const int lane = threadIdx.x & 63;
    const int wid  = threadIdx.x >> 6;
    if (lane == 0) {
        #pragma unroll
        for (int k = 0; k < NACC; ++k) red[wid][k] = acc[k];
    }
    __syncthreads();

    if (threadIdx.x == 0) {
        double S[NACC];
        #pragma unroll
        for (int k = 0; k < NACC; ++k) {
            double t = 0.0;
            #pragma unroll
            for (int w = 0; w < NTHREADS / 64; ++w) t += red[w][k];
            S[k] = t;
        }
        const double M  = (double)M_ELEMS;
        const double S3 = S[2] + M * EPS;   // sum of (1/sqrt(lam1) + eps)
        const double S4 = S[3] + M * EPS;
        double loss = (S[0] * S3 + S[1] * S4 + 0.5 * OMEGA * S[4]) / M;
        out[0] = (float)loss;
    }
}

extern "C" void kernel_launch(void* const* d_in, const int* in_sizes, int n_in,
                              void* d_out, int out_size, void* d_ws, size_t ws_size,
                              hipStream_t stream) {
    const f2* pred = (const f2*)d_in[0];   // (B,N,2)   = M f2
    const f4* cov  = (const f4*)d_in[1];   // (B,N,2,2) = M f4
    const f2* tgt  = (const f2*)d_in[2];   // (B,N,2)   = M f2
    float* out      = (float*)d_out;
    float* partials = (float*)d_ws;        // NBLOCKS*NACC floats (80 KB)

    star_partial<<<NBLOCKS, NTHREADS, 0, stream>>>(pred, cov, tgt, partials);
    star_final<<<1, NTHREADS, 0, stream>>>(partials, out, NBLOCKS);
}